// Round 10
// baseline (128.932 us; speedup 1.0000x reference)
//
#include <hip/hip_runtime.h>

#define BB 32
#define HH 256
#define WW 256
#define CC 4
#define KH 5
#define KW 5
#define FF 8
#define HO (HH - KH + 1)   // 252
#define WO (WW - KW + 1)   // 252
#define NTAP (KH * KW)     // 25

typedef _Float16 h2      __attribute__((ext_vector_type(2)));
typedef __fp16   fp16x2  __attribute__((ext_vector_type(2)));

static __device__ __forceinline__ h2 pkrtz(float a, float b) {
    fp16x2 r = __builtin_amdgcn_cvt_pkrtz(a, b);
    return __builtin_bit_cast(h2, r);
}

// --- Kernel A: pre-pack weights into f16 channel pairs in d_ws. ---
// dword i = tap*16 + f*2 + pair : pk(k[tap, 2*pair, f], k[tap, 2*pair+1, f])
// 400 dwords = 1600 B.
__global__ void pack_kernel(const float* __restrict__ k, unsigned int* __restrict__ kp)
{
    int i = blockIdx.x * blockDim.x + threadIdx.x;
    if (i >= NTAP * 16) return;
    int t = i >> 4;          // tap
    int r = i & 15;
    int f = r >> 1;
    int p = r & 1;           // channel pair
    float a = k[(t * CC + 2 * p + 0) * FF + f];
    float b = k[(t * CC + 2 * p + 1) * FF + f];
    kp[i] = __builtin_bit_cast(unsigned int, pkrtz(a, b));
}

// --- Kernel B: one output pixel per thread (R1's proven 94%-busy shape),
// packed-f16 channel-pair math (R3's proven core). Weights are wave-uniform
// -> s_load_dwordx16 per tap, consumed as SGPR operands of v_pk_*_f16.
// Pixel loads converted immediately: minimal register liveness (target
// VGPR <= 32 so the R1 occupancy regime is preserved). No hand pipeline,
// no fences (R7/R8/R9 post-mortems).
__global__ __launch_bounds__(256) void erosion2d_f16(
    const float* __restrict__ x,
    const h2* __restrict__ k2,        // d_ws, layout above
    float* __restrict__ out)
{
    // Grid is exact: 7938 * 256 == 32 * 252 * 252.
    int tid = blockIdx.x * blockDim.x + threadIdx.x;

    int b   = tid / (HO * WO);
    int rem = tid - b * (HO * WO);
    int y   = rem / WO;
    int xo  = rem - y * WO;

    const float* xb = x + (((size_t)b * HH + y) * WW + xo) * CC;

    h2 acc[FF];

#pragma unroll
    for (int dy = 0; dy < KH; ++dy) {
#pragma unroll
        for (int dx = 0; dx < KW; ++dx) {
            const float4 px = *reinterpret_cast<const float4*>(xb + (dy * WW + dx) * CC);
            const h2 c01 = pkrtz(px.x, px.y);
            const h2 c23 = pkrtz(px.z, px.w);
            const h2* kt = k2 + (dy * KW + dx) * 16;   // 16 dwords, one s_load_dwordx16
#pragma unroll
            for (int f = 0; f < FF; ++f) {
                h2 d01 = c01 - kt[f * 2 + 0];
                h2 d23 = c23 - kt[f * 2 + 1];
                h2 m   = __builtin_elementwise_min(d01, d23);
                if (dy == 0 && dx == 0)
                    acc[f] = m;                        // first tap initializes
                else
                    acc[f] = __builtin_elementwise_min(acc[f], m);
            }
        }
    }

    // Epilogue: horizontal min over the channel pair, f16 -> f32, 32 B store.
    float rr[FF];
#pragma unroll
    for (int f = 0; f < FF; ++f) {
        _Float16 m = __builtin_elementwise_min(acc[f][0], acc[f][1]);
        rr[f] = (float)m;
    }
    float* op = out + (size_t)tid * FF;
    *reinterpret_cast<float4*>(op)     = make_float4(rr[0], rr[1], rr[2], rr[3]);
    *reinterpret_cast<float4*>(op + 4) = make_float4(rr[4], rr[5], rr[6], rr[7]);
}

extern "C" void kernel_launch(void* const* d_in, const int* in_sizes, int n_in,
                              void* d_out, int out_size, void* d_ws, size_t ws_size,
                              hipStream_t stream) {
    const float* x = (const float*)d_in[0];
    const float* k = (const float*)d_in[1];
    float* out = (float*)d_out;

    pack_kernel<<<2, 256, 0, stream>>>(k, (unsigned int*)d_ws);

    const int total = BB * HO * WO;                  // 2,032,128 threads
    const int block = 256;
    const int grid  = total / block;                 // 7938 blocks, exact
    erosion2d_f16<<<grid, block, 0, stream>>>(x, (const h2*)d_ws, out);
}

// Round 11
// 85.655 us; speedup vs baseline: 1.5053x; 1.5053x over previous
//
#include <hip/hip_runtime.h>

#define BB 32
#define HH 256
#define WW 256
#define CC 4
#define KH 5
#define KW 5
#define FF 8
#define HO (HH - KH + 1)   // 252
#define WO (WW - KW + 1)   // 252
#define NTAP (KH * KW)     // 25
#define SLEN 20            // outputs per strip (multiple of 5 for static slots)
#define NS 13              // strips per row; last strip clamped (8-col overlap, benign)

typedef _Float16 h2      __attribute__((ext_vector_type(2)));
typedef __fp16   fp16x2  __attribute__((ext_vector_type(2)));

static __device__ __forceinline__ h2 pkrtz(float a, float b) {
    fp16x2 r = __builtin_amdgcn_cvt_pkrtz(a, b);
    return __builtin_bit_cast(h2, r);
}

// One phase of the 5-phase sliding window. P is compile-time: all window-slot
// indices are static (no dynamic ext_vector indexing -> no scratch, rule #20).
template<int P>
__device__ __forceinline__ void phase(
    int ii, const float* __restrict__ xb, float* __restrict__ ob,
    h2 (&win01)[5][5], h2 (&win23)[5][5],
    const h2 (&w01)[NTAP], const h2 (&w23)[NTAP])
{
    // Issue next-column loads first (5 rows); consumed only after compute.
    float4 n0, n1, n2, n3, n4;
    const bool ld = (ii + P + 5) < (SLEN + 4);   // cols needed: 0..SLEN+3
    if (ld) {
        const float* nc = xb + (ii + P + 5) * CC;
        n0 = *reinterpret_cast<const float4*>(nc + 0 * WW * CC);
        n1 = *reinterpret_cast<const float4*>(nc + 1 * WW * CC);
        n2 = *reinterpret_cast<const float4*>(nc + 2 * WW * CC);
        n3 = *reinterpret_cast<const float4*>(nc + 3 * WW * CC);
        n4 = *reinterpret_cast<const float4*>(nc + 4 * WW * CC);
    }

    // Compute output x0+ii+P from window cols [ii+P .. ii+P+4]
    // (col c sits in slot (P + c-offset) % 5, all static).
    h2 a01 = win01[P % 5][0] - w01[0];
    h2 a23 = win23[P % 5][0] - w23[0];
#pragma unroll
    for (int r = 0; r < KH; ++r) {
#pragma unroll
        for (int cc = 0; cc < KW; ++cc) {
            if (r == 0 && cc == 0) continue;
            const int tap = r * KW + cc;
            const int cs  = (P + cc) % 5;
            h2 d01 = win01[cs][r] - w01[tap];
            h2 d23 = win23[cs][r] - w23[tap];
            a01 = __builtin_elementwise_min(a01, d01);
            a23 = __builtin_elementwise_min(a23, d23);
        }
    }
    h2 m = __builtin_elementwise_min(a01, a23);
    ob[(ii + P) * FF] = fminf((float)m[0], (float)m[1]);

    // Retire oldest column: slot P <- col ii+P+5.
    if (ld) {
        win01[P][0] = pkrtz(n0.x, n0.y); win23[P][0] = pkrtz(n0.z, n0.w);
        win01[P][1] = pkrtz(n1.x, n1.y); win23[P][1] = pkrtz(n1.z, n1.w);
        win01[P][2] = pkrtz(n2.x, n2.y); win23[P][2] = pkrtz(n2.z, n2.w);
        win01[P][3] = pkrtz(n3.x, n3.y); win23[P][3] = pkrtz(n3.z, n3.w);
        win01[P][4] = pkrtz(n4.x, n4.y); win23[P][4] = pkrtz(n4.z, n4.w);
    }
}

// Weight-resident sliding-window erosion: thread = (b, y, strip, f).
// 50 weight dwords live in VGPRs for the whole kernel (read once from the
// fused LDS pack) -> zero steady-state weight fetches (R6 spent ~31us of
// LDS-pipe time re-reading weights per tap).
__global__ __launch_bounds__(256) void erosion2d_sw(
    const float* __restrict__ x,
    const float* __restrict__ k,
    float* __restrict__ out)
{
    __shared__ unsigned int lw[NTAP * 16];   // [tap][f][pair], 1.6 KB
    for (int i = threadIdx.x; i < NTAP * 16; i += 256) {
        int t  = i >> 4;
        int rr = i & 15;
        int f  = rr >> 1;
        int p  = rr & 1;
        lw[i] = __builtin_bit_cast(unsigned int,
                pkrtz(k[(t * CC + 2 * p + 0) * FF + f],
                      k[(t * CC + 2 * p + 1) * FF + f]));
    }
    __syncthreads();

    // Grid exact: 3276 * 256 == 32 * 252 * 13 * 8.
    const int tid = blockIdx.x * 256 + threadIdx.x;
    const int f   = tid & 7;           // lanes 0..7: f 0..7 of same strip
    const int q   = tid >> 3;
    const int s   = q % NS;
    const int r0  = q / NS;            // b*HO + y
    const int b   = r0 / HO;
    const int y   = r0 - b * HO;
    int x0 = s * SLEN;
    if (x0 > WO - SLEN) x0 = WO - SLEN;   // s==12 -> 232 (8-col overlap rewrite)

    // Per-filter weights -> registers (one-time; 25x ds_read_b64, broadcast).
    const h2* lwh = reinterpret_cast<const h2*>(lw);
    h2 w01[NTAP], w23[NTAP];
#pragma unroll
    for (int t = 0; t < NTAP; ++t) {
        w01[t] = lwh[t * 16 + f * 2 + 0];
        w23[t] = lwh[t * 16 + f * 2 + 1];
    }

    const float* xb = x + (((size_t)b * HH + y) * WW + x0) * CC;
    float* ob = out + ((size_t)r0 * WO + x0) * FF + f;

    // Prime the window: cols 0..4, rows 0..4.
    h2 win01[5][5], win23[5][5];       // [col slot][row]
#pragma unroll
    for (int c = 0; c < 5; ++c)
#pragma unroll
        for (int r = 0; r < 5; ++r) {
            float4 px = *reinterpret_cast<const float4*>(xb + (r * WW + c) * CC);
            win01[c][r] = pkrtz(px.x, px.y);
            win23[c][r] = pkrtz(px.z, px.w);
        }

#pragma unroll 1   // keep 5-phase blocks rolled: no cross-block load hoisting
    for (int ii = 0; ii < SLEN; ii += 5) {
        phase<0>(ii, xb, ob, win01, win23, w01, w23);
        phase<1>(ii, xb, ob, win01, win23, w01, w23);
        phase<2>(ii, xb, ob, win01, win23, w01, w23);
        phase<3>(ii, xb, ob, win01, win23, w01, w23);
        phase<4>(ii, xb, ob, win01, win23, w01, w23);
    }
}

extern "C" void kernel_launch(void* const* d_in, const int* in_sizes, int n_in,
                              void* d_out, int out_size, void* d_ws, size_t ws_size,
                              hipStream_t stream) {
    const float* x = (const float*)d_in[0];
    const float* k = (const float*)d_in[1];
    float* out = (float*)d_out;

    const int total = BB * HO * NS * FF;             // 838,656 threads
    const int block = 256;
    const int grid  = total / block;                 // 3276 blocks, exact
    erosion2d_sw<<<grid, block, 0, stream>>>(x, k, out);
}